// Round 10
// baseline (641.840 us; speedup 1.0000x reference)
//
#include <hip/hip_runtime.h>
#include <hip/hip_cooperative_groups.h>

namespace cg = cooperative_groups;

#define N_ 512
#define D_ 128
#define LOG2E 1.44269504088896f

// ws: xp_t bf16 TRANSPOSED [inst][f=128][s=512], 64 inst = 8,388,608 B.
// Single cooperative kernel: proj -> grid.sync -> attn -> grid.sync ->
// combine (in place on d_out). Fallback: same phases as 3 plain kernels.

typedef __attribute__((ext_vector_type(8))) short short8;
typedef __attribute__((ext_vector_type(4))) float floatx4;
typedef __attribute__((ext_vector_type(4))) unsigned int uintx4;

#if defined(__has_builtin)
#if __has_builtin(__builtin_amdgcn_exp2f)
#define EXP2F(x) __builtin_amdgcn_exp2f(x)
#else
#define EXP2F(x) exp2f(x)
#endif
#else
#define EXP2F(x) exp2f(x)
#endif

__device__ __forceinline__ unsigned short f2bf(float f) {
    unsigned int u = __float_as_uint(f);
    u += 0x7fffu + ((u >> 16) & 1u);
    return (unsigned short)(u >> 16);
}
__device__ __forceinline__ float bflo(unsigned int u) { return __uint_as_float(u << 16); }
__device__ __forceinline__ float bfhi(unsigned int u) { return __uint_as_float(u & 0xffff0000u); }
__device__ __forceinline__ float bf1(unsigned short s) { return __uint_as_float(((unsigned int)s) << 16); }

// ---------------------------------------------------------------------------
// Phase 1: proj via MFMA, no LDS/barriers. 2 blocks per (inst, 64-row ntile):
// half = bid&1 covers 4 of 8 f-tiles. A-frags in-lane from fp32 x; B-frags
// in-lane from fp32 W (L2-hot). xp_t[inst][f][n] = sum_c x*W + pb, bf16.
// ---------------------------------------------------------------------------
__device__ __forceinline__ void proj_phase(
    const int bid, const int t,
    const float* __restrict__ x, const float* __restrict__ W,
    const float* __restrict__ pb, unsigned short* __restrict__ xpt)
{
    const int unit = bid >> 1;      // 0..511
    const int half = bid & 1;
    const int ntile = unit & 7;
    const int inst  = unit >> 3;    // 0..63
    const int j = inst & 1;
    const int bi = inst >> 1;
    const int ij = (bi & 1) * 2 + j;
    const int wave = t >> 6, L = t & 63, n = L & 15, q = L >> 4;

    const int n0w = ntile * 64 + wave * 16;
    const float* xrow = x + ((size_t)bi * N_ + n0w + n) * D_ + q * 8;
    short8 Af[4];
#pragma unroll
    for (int kc = 0; kc < 4; ++kc) {
        const float4 a0 = *(const float4*)(xrow + kc * 32);
        const float4 a1 = *(const float4*)(xrow + kc * 32 + 4);
        uintx4 au;
        au.x = f2bf(a0.x) | ((unsigned int)f2bf(a0.y) << 16);
        au.y = f2bf(a0.z) | ((unsigned int)f2bf(a0.w) << 16);
        au.z = f2bf(a1.x) | ((unsigned int)f2bf(a1.y) << 16);
        au.w = f2bf(a1.z) | ((unsigned int)f2bf(a1.w) << 16);
        Af[kc] = __builtin_bit_cast(short8, au);
    }

    const float* wb = W + (size_t)ij * D_ * D_;
#pragma unroll
    for (int ft = 0; ft < 4; ++ft) {
        const int fg = (half * 4 + ft) * 16 + n;
        const float* wrow = wb + (size_t)fg * D_ + q * 8;
        floatx4 C = (floatx4){0.f, 0.f, 0.f, 0.f};
#pragma unroll
        for (int kc = 0; kc < 4; ++kc) {
            const float4 b0 = *(const float4*)(wrow + kc * 32);
            const float4 b1 = *(const float4*)(wrow + kc * 32 + 4);
            uintx4 bu;
            bu.x = f2bf(b0.x) | ((unsigned int)f2bf(b0.y) << 16);
            bu.y = f2bf(b0.z) | ((unsigned int)f2bf(b0.w) << 16);
            bu.z = f2bf(b1.x) | ((unsigned int)f2bf(b1.y) << 16);
            bu.w = f2bf(b1.z) | ((unsigned int)f2bf(b1.w) << 16);
            C = __builtin_amdgcn_mfma_f32_16x16x32_bf16(
                Af[kc], __builtin_bit_cast(short8, bu), C, 0, 0, 0);
        }
        const float pbv = pb[ij * D_ + fg];
        uint2 pk;
        pk.x = f2bf(C[0] + pbv) | ((unsigned int)f2bf(C[1] + pbv) << 16);
        pk.y = f2bf(C[2] + pbv) | ((unsigned int)f2bf(C[3] + pbv) << 16);
        *(uint2*)&xpt[((size_t)inst * D_ + fg) * N_ + n0w + q * 4] = pk;
    }
}

// ---------------------------------------------------------------------------
// Phase 2: attention via MFMA (R9 body). tile = bid&31, bi = bid>>5.
// ---------------------------------------------------------------------------
__device__ __forceinline__ void attn_phase(
    const int bid, const int t,
    const unsigned short* __restrict__ xpt,
    const int* __restrict__ A,
    const float* __restrict__ att_src,
    const float* __restrict__ att_dst,
    const float* __restrict__ bias,
    float* __restrict__ hout)
{
    __shared__ float ss_t[8][N_];
    __shared__ unsigned int mask_l[2][N_];
    __shared__ float sd_l[8][16];
    __shared__ float z_l[8][16];
    __shared__ float as_l[128];
    __shared__ float ad_l[128];

    const int tile = bid & 31;
    const int bi   = bid >> 5;
    const int i_ = bi & 1;
    const int d0 = tile * 16;
    const int wave = t >> 6, L = t & 63, n = L & 15, q = L >> 4;
    const int h0 = wave * 2;

#pragma unroll
    for (int rep = 0; rep < 2; ++rep) {
        const int s = t + rep * 256;
        const int* Ar = A + ((size_t)bi * N_ + s) * N_ + d0;
        unsigned int m0 = 0, m1 = 0;
#pragma unroll
        for (int g = 0; g < 4; ++g) {
            const int4 v = *(const int4*)(Ar + g * 4);
            const int k = g * 4;
            if (v.x == 2 || v.x == 4) m0 |= 1u << (k + 0);
            if (v.x == 3 || v.x == 4) m1 |= 1u << (k + 0);
            if (v.y == 2 || v.y == 4) m0 |= 1u << (k + 1);
            if (v.y == 3 || v.y == 4) m1 |= 1u << (k + 1);
            if (v.z == 2 || v.z == 4) m0 |= 1u << (k + 2);
            if (v.z == 3 || v.z == 4) m1 |= 1u << (k + 2);
            if (v.w == 2 || v.w == 4) m0 |= 1u << (k + 3);
            if (v.w == 3 || v.w == 4) m1 |= 1u << (k + 3);
        }
        mask_l[0][s] = m0;
        mask_l[1][s] = m1;
    }

    float hacc[2][4];
#pragma unroll
    for (int a = 0; a < 2; ++a)
#pragma unroll
        for (int b = 0; b < 4; ++b) hacc[a][b] = 0.f;

    for (int j = 0; j < 2; ++j) {
        const int inst = bi * 2 + j;
        const int ij = i_ * 2 + j;
        const unsigned short* xpi = xpt + (size_t)inst * D_ * N_;

        __syncthreads();
        if (t < 128) {
            as_l[t] = att_src[ij * D_ + t] * LOG2E;
            ad_l[t] = att_dst[ij * D_ + t] * LOG2E;
        }
        __syncthreads();

        {
            const int hh = t >> 5;
            const int sb = (t & 31) * 16;
            float accs[16];
#pragma unroll
            for (int k = 0; k < 16; ++k) accs[k] = 0.f;
#pragma unroll 4
            for (int f = 0; f < 16; ++f) {
                const unsigned short* row = xpi + (size_t)(hh * 16 + f) * N_ + sb;
                const uint4 a0 = *(const uint4*)row;
                const uint4 a1 = *(const uint4*)(row + 8);
                const float av = as_l[hh * 16 + f];
                accs[0]  += bflo(a0.x) * av; accs[1]  += bfhi(a0.x) * av;
                accs[2]  += bflo(a0.y) * av; accs[3]  += bfhi(a0.y) * av;
                accs[4]  += bflo(a0.z) * av; accs[5]  += bfhi(a0.z) * av;
                accs[6]  += bflo(a0.w) * av; accs[7]  += bfhi(a0.w) * av;
                accs[8]  += bflo(a1.x) * av; accs[9]  += bfhi(a1.x) * av;
                accs[10] += bflo(a1.y) * av; accs[11] += bfhi(a1.y) * av;
                accs[12] += bflo(a1.z) * av; accs[13] += bfhi(a1.z) * av;
                accs[14] += bflo(a1.w) * av; accs[15] += bfhi(a1.w) * av;
            }
#pragma unroll
            for (int k = 0; k < 16; ++k) ss_t[hh][sb + k] = accs[k];
        }
        if (t < 128) {
            const int dd = t >> 3;
            const int hh = t & 7;
            float s = 0.f;
#pragma unroll
            for (int f = 0; f < 16; ++f)
                s += bf1(xpi[(size_t)(hh * 16 + f) * N_ + d0 + dd]) * ad_l[hh * 16 + f];
            sd_l[hh][dd] = s;
        }
        __syncthreads();

        const float sdv[2] = { sd_l[h0][n], sd_l[h0 + 1][n] };

        floatx4 Cacc[2] = { (floatx4){0.f,0.f,0.f,0.f}, (floatx4){0.f,0.f,0.f,0.f} };
        float zacc[2] = { 0.f, 0.f };

        for (int c = 0; c < 16; ++c) {
            const int sq = c * 32 + q * 8;
            short8 Bf[2];
            Bf[0] = *(const short8*)(xpi + (size_t)(h0 * 16 + n) * N_ + sq);
            Bf[1] = *(const short8*)(xpi + (size_t)((h0 + 1) * 16 + n) * N_ + sq);
            const uint4 m0v = *(const uint4*)&mask_l[j][sq];
            const uint4 m1v = *(const uint4*)&mask_l[j][sq + 4];
            const unsigned int mw[8] = { m0v.x, m0v.y, m0v.z, m0v.w,
                                         m1v.x, m1v.y, m1v.z, m1v.w };
#pragma unroll
            for (int hh2 = 0; hh2 < 2; ++hh2) {
                const float4 s0v = *(const float4*)&ss_t[h0 + hh2][sq];
                const float4 s1v = *(const float4*)&ss_t[h0 + hh2][sq + 4];
                const float ssv[8] = { s0v.x, s0v.y, s0v.z, s0v.w,
                                       s1v.x, s1v.y, s1v.z, s1v.w };
                unsigned int wt[8];
#pragma unroll
                for (int idx = 0; idx < 8; ++idx) {
                    const float z0 = ssv[idx] + sdv[hh2];
                    const float zr = fmaxf(z0, 0.2f * z0);
                    const float e = EXP2F(zr);
                    const float w = ((mw[idx] >> n) & 1u) ? e : 1.0f;
                    wt[idx] = __float_as_uint(w) & 0xffff0000u;
                    zacc[hh2] += __uint_as_float(wt[idx]);
                }
                uintx4 au;
                au.x = __builtin_amdgcn_perm(wt[1], wt[0], 0x07060302);
                au.y = __builtin_amdgcn_perm(wt[3], wt[2], 0x07060302);
                au.z = __builtin_amdgcn_perm(wt[5], wt[4], 0x07060302);
                au.w = __builtin_amdgcn_perm(wt[7], wt[6], 0x07060302);
                Cacc[hh2] = __builtin_amdgcn_mfma_f32_16x16x32_bf16(
                    __builtin_bit_cast(short8, au), Bf[hh2], Cacc[hh2], 0, 0, 0);
            }
        }

#pragma unroll
        for (int hh2 = 0; hh2 < 2; ++hh2) {
            float z = zacc[hh2];
            z += __shfl_xor(z, 16);
            z += __shfl_xor(z, 32);
            zacc[hh2] = z;
        }
        if (q == 0) { z_l[h0][n] = zacc[0]; z_l[h0 + 1][n] = zacc[1]; }

#pragma unroll
        for (int hh2 = 0; hh2 < 2; ++hh2) {
            const int h = h0 + hh2;
            const float bv = bias[ij * D_ + h * 16 + n];
            const uint2 sv = *(const uint2*)(xpi + (size_t)(h * 16 + n) * N_ + d0 + q * 4);
            const float selfv[4] = { bflo(sv.x), bfhi(sv.x), bflo(sv.y), bfhi(sv.y) };
#pragma unroll
            for (int reg = 0; reg < 4; ++reg) {
                const float Zi = 1.0f / z_l[h][q * 4 + reg];
                hacc[hh2][reg] += Cacc[hh2][reg] * Zi + selfv[reg] + bv;
            }
        }
    }

#pragma unroll
    for (int hh2 = 0; hh2 < 2; ++hh2)
#pragma unroll
        for (int reg = 0; reg < 4; ++reg)
            hout[((size_t)bi * N_ + d0 + q * 4 + reg) * D_ + (h0 + hh2) * 16 + n]
                = hacc[hh2][reg];
}

// ---------------------------------------------------------------------------
// Phase 3: in-place mix on d_out (thread owns both i slices of one b).
// ---------------------------------------------------------------------------
__device__ __forceinline__ void combine_phase(const int bid, const int t,
                                              float* __restrict__ h)
{
    const int idx = bid * 256 + t;
    const int b = idx >> 14;
    const int r = idx & 16383;
    float4* p0 = (float4*)h + (size_t)b * 32768 + r;
    float4* p1 = p0 + 16384;
    const float4 a = *p0;
    const float4 o = *p1;
    float4 r0, r1;
    r0.x = 1.5f * a.x + 0.5f * o.x;  r1.x = 1.5f * o.x + 0.5f * a.x;
    r0.y = 1.5f * a.y + 0.5f * o.y;  r1.y = 1.5f * o.y + 0.5f * a.y;
    r0.z = 1.5f * a.z + 0.5f * o.z;  r1.z = 1.5f * o.z + 0.5f * a.z;
    r0.w = 1.5f * a.w + 0.5f * o.w;  r1.w = 1.5f * o.w + 0.5f * a.w;
    *p0 = r0;
    *p1 = r1;
}

// ---------------------------------------------------------------------------
// Fused cooperative kernel (1024 blocks x 256 thr, 4 blocks/CU).
// ---------------------------------------------------------------------------
__global__ __launch_bounds__(256) void fused_kernel(
    const float* __restrict__ x, const int* __restrict__ A,
    const float* __restrict__ W, const float* __restrict__ pb,
    const float* __restrict__ as_, const float* __restrict__ ad_,
    const float* __restrict__ bs,
    unsigned short* __restrict__ xpt, float* __restrict__ out)
{
    cg::grid_group grid = cg::this_grid();
    const int bid = blockIdx.x, t = threadIdx.x;
    proj_phase(bid, t, x, W, pb, xpt);
    __threadfence();
    grid.sync();
    attn_phase(bid, t, xpt, A, as_, ad_, bs, out);
    __threadfence();
    grid.sync();
    combine_phase(bid, t, out);
}

// -------- fallback plain kernels (same phases, 3 dispatches) --------
__global__ __launch_bounds__(256) void proj_kernel(
    const float* __restrict__ x, const float* __restrict__ W,
    const float* __restrict__ pb, unsigned short* __restrict__ xpt)
{ proj_phase(blockIdx.x, threadIdx.x, x, W, pb, xpt); }

__global__ __launch_bounds__(256) void attn_kernel(
    const unsigned short* __restrict__ xpt, const int* __restrict__ A,
    const float* __restrict__ as_, const float* __restrict__ ad_,
    const float* __restrict__ bs, float* __restrict__ out)
{ attn_phase(blockIdx.x, threadIdx.x, xpt, A, as_, ad_, bs, out); }

__global__ __launch_bounds__(256) void combine_kernel(float* __restrict__ h)
{ combine_phase(blockIdx.x, threadIdx.x, h); }

extern "C" void kernel_launch(void* const* d_in, const int* in_sizes, int n_in,
                              void* d_out, int out_size, void* d_ws, size_t ws_size,
                              hipStream_t stream)
{
    const float* x   = (const float*)d_in[0];
    const int*   A   = (const int*)d_in[1];
    const float* W   = (const float*)d_in[2];
    const float* pb  = (const float*)d_in[3];
    const float* as_ = (const float*)d_in[4];
    const float* ad_ = (const float*)d_in[5];
    const float* bs  = (const float*)d_in[6];

    unsigned short* xpt = (unsigned short*)d_ws;   // 8,388,608 B
    float* h = (float*)d_out;

    void* args[9] = { (void*)&x, (void*)&A, (void*)&W, (void*)&pb,
                      (void*)&as_, (void*)&ad_, (void*)&bs,
                      (void*)&xpt, (void*)&h };
    hipError_t err = hipLaunchCooperativeKernel(
        (const void*)fused_kernel, dim3(1024), dim3(256), args, 0, stream);
    if (err != hipSuccess) {
        proj_kernel<<<1024, 256, 0, stream>>>(x, W, pb, xpt);
        attn_kernel<<<1024, 256, 0, stream>>>(xpt, A, as_, ad_, bs, h);
        combine_kernel<<<1024, 256, 0, stream>>>(h);
    }
}

// Round 11
// 168.075 us; speedup vs baseline: 3.8188x; 3.8188x over previous
//
#include <hip/hip_runtime.h>

#define N_ 512
#define D_ 128
#define LOG2E 1.44269504088896f

// ws: [0, 8 MB)   xp_t bf16 TRANSPOSED [inst][f=128][s=512]  (8,388,608 B)
//     [8, 9 MB)   ss_g fp32 [inst][h=8][s=512], log2-domain  (1,048,576 B)
// h staged in d_out; combine mixes in place. 3 plain dispatches
// (cooperative grid.sync measured ~230us/sync on this grid -> reverted).

typedef __attribute__((ext_vector_type(8))) short short8;
typedef __attribute__((ext_vector_type(4))) float floatx4;
typedef __attribute__((ext_vector_type(4))) unsigned int uintx4;

#if defined(__has_builtin)
#if __has_builtin(__builtin_amdgcn_exp2f)
#define EXP2F(x) __builtin_amdgcn_exp2f(x)
#else
#define EXP2F(x) exp2f(x)
#endif
#else
#define EXP2F(x) exp2f(x)
#endif

__device__ __forceinline__ unsigned short f2bf(float f) {
    unsigned int u = __float_as_uint(f);
    u += 0x7fffu + ((u >> 16) & 1u);
    return (unsigned short)(u >> 16);
}
__device__ __forceinline__ float bflo(unsigned int u) { return __uint_as_float(u << 16); }
__device__ __forceinline__ float bfhi(unsigned int u) { return __uint_as_float(u & 0xffff0000u); }
__device__ __forceinline__ float bf1(unsigned short s) { return __uint_as_float(((unsigned int)s) << 16); }

// ---------------------------------------------------------------------------
// Kernel 1: proj via MFMA, no LDS/barriers; fused ss reduction.
// 2 blocks per (inst, 64-row ntile): half = bid&1 covers 4 f-tiles (= 4 heads
// h = half*4+ft, since a head is exactly 16 f). A-frags in-lane from fp32 x;
// B-frags in-lane from fp32 W (L2-hot). Epilogue: xp_t bf16 store + in-quad
// 16-lane shfl reduction of ss[n,h] = sum_f xp[n,f]*as[f]*log2e -> ss_g.
// C/D: col=lane&15 (f), row=q*4+reg (n row) [m89-verified].
// ---------------------------------------------------------------------------
__global__ __launch_bounds__(256) void proj_kernel(
    const float* __restrict__ x, const float* __restrict__ W,
    const float* __restrict__ pb, const float* __restrict__ att_src,
    unsigned short* __restrict__ xpt, float* __restrict__ ssg)
{
    const int bid = blockIdx.x;
    const int unit = bid >> 1;      // 0..511
    const int half = bid & 1;
    const int ntile = unit & 7;
    const int inst  = unit >> 3;    // 0..63
    const int j = inst & 1;
    const int bi = inst >> 1;
    const int ij = (bi & 1) * 2 + j;
    const int t = threadIdx.x;
    const int wave = t >> 6, L = t & 63, n = L & 15, q = L >> 4;

    const int n0w = ntile * 64 + wave * 16;
    const float* xrow = x + ((size_t)bi * N_ + n0w + n) * D_ + q * 8;
    short8 Af[4];
#pragma unroll
    for (int kc = 0; kc < 4; ++kc) {
        const float4 a0 = *(const float4*)(xrow + kc * 32);
        const float4 a1 = *(const float4*)(xrow + kc * 32 + 4);
        uintx4 au;
        au.x = f2bf(a0.x) | ((unsigned int)f2bf(a0.y) << 16);
        au.y = f2bf(a0.z) | ((unsigned int)f2bf(a0.w) << 16);
        au.z = f2bf(a1.x) | ((unsigned int)f2bf(a1.y) << 16);
        au.w = f2bf(a1.z) | ((unsigned int)f2bf(a1.w) << 16);
        Af[kc] = __builtin_bit_cast(short8, au);
    }

    const float* wb = W + (size_t)ij * D_ * D_;
#pragma unroll
    for (int ft = 0; ft < 4; ++ft) {
        const int fg = (half * 4 + ft) * 16 + n;
        const float* wrow = wb + (size_t)fg * D_ + q * 8;
        floatx4 C = (floatx4){0.f, 0.f, 0.f, 0.f};
#pragma unroll
        for (int kc = 0; kc < 4; ++kc) {
            const float4 b0 = *(const float4*)(wrow + kc * 32);
            const float4 b1 = *(const float4*)(wrow + kc * 32 + 4);
            uintx4 bu;
            bu.x = f2bf(b0.x) | ((unsigned int)f2bf(b0.y) << 16);
            bu.y = f2bf(b0.z) | ((unsigned int)f2bf(b0.w) << 16);
            bu.z = f2bf(b1.x) | ((unsigned int)f2bf(b1.y) << 16);
            bu.w = f2bf(b1.z) | ((unsigned int)f2bf(b1.w) << 16);
            C = __builtin_amdgcn_mfma_f32_16x16x32_bf16(
                Af[kc], __builtin_bit_cast(short8, bu), C, 0, 0, 0);
        }
        const float pbv = pb[ij * D_ + fg];
        float xp0 = C[0] + pbv, xp1 = C[1] + pbv;
        float xp2 = C[2] + pbv, xp3 = C[3] + pbv;
        uint2 pk;
        pk.x = f2bf(xp0) | ((unsigned int)f2bf(xp1) << 16);
        pk.y = f2bf(xp2) | ((unsigned int)f2bf(xp3) << 16);
        *(uint2*)&xpt[((size_t)inst * D_ + fg) * N_ + n0w + q * 4] = pk;

        // ss reduction: for each reg, sum (xp * as[fg]) over the 16 n-lanes
        const float asv = att_src[ij * D_ + fg];
        float s0 = xp0 * asv, s1 = xp1 * asv, s2 = xp2 * asv, s3 = xp3 * asv;
#pragma unroll
        for (int off = 1; off < 16; off <<= 1) {
            s0 += __shfl_xor(s0, off);
            s1 += __shfl_xor(s1, off);
            s2 += __shfl_xor(s2, off);
            s3 += __shfl_xor(s3, off);
        }
        if (n < 4) {
            const float v = (n == 0) ? s0 : (n == 1) ? s1 : (n == 2) ? s2 : s3;
            ssg[((size_t)inst * 8 + half * 4 + ft) * N_ + n0w + q * 4 + n] = v * LOG2E;
        }
    }
}

// ---------------------------------------------------------------------------
// Kernel 2: attention via MFMA. Block = (bi = bid>>5, 16-dst tile = bid&31);
// 4 waves, wave owns 2 heads. ss comes precomputed from proj (16 KB LDS copy
// per conv). w A-fragments built in-lane (8 exp2 per MFMA) against B = xp_t
// rows (16 B global loads, software-prefetched). w truncated to bf16 so Z
// and the numerator match. No barriers in the K-loop.
// Masked entries: w = exp(0) = 1; softmax over all 512 src.
// ---------------------------------------------------------------------------
__global__ __launch_bounds__(256) void attn_kernel(
    const unsigned short* __restrict__ xpt,
    const float* __restrict__ ssg,
    const int* __restrict__ A,
    const float* __restrict__ att_dst,
    const float* __restrict__ bias,
    float* __restrict__ hout)
{
    __shared__ float ss_t[8 * N_];           // 16 KB [h][s], log2-domain
    __shared__ unsigned int mask_l[2][N_];   // 4 KB
    __shared__ float sd_l[8][16];
    __shared__ float z_l[8][16];
    __shared__ float ad_l[128];

    const int bid = blockIdx.x;
    const int tile = bid & 31;
    const int bi   = bid >> 5;
    const int i_ = bi & 1;
    const int d0 = tile * 16;
    const int t = threadIdx.x;
    const int wave = t >> 6, L = t & 63, n = L & 15, q = L >> 4;
    const int h0 = wave * 2;

#pragma unroll
    for (int rep = 0; rep < 2; ++rep) {
        const int s = t + rep * 256;
        const int* Ar = A + ((size_t)bi * N_ + s) * N_ + d0;
        unsigned int m0 = 0, m1 = 0;
#pragma unroll
        for (int g = 0; g < 4; ++g) {
            const int4 v = *(const int4*)(Ar + g * 4);
            const int k = g * 4;
            if (v.x == 2 || v.x == 4) m0 |= 1u << (k + 0);
            if (v.x == 3 || v.x == 4) m1 |= 1u << (k + 0);
            if (v.y == 2 || v.y == 4) m0 |= 1u << (k + 1);
            if (v.y == 3 || v.y == 4) m1 |= 1u << (k + 1);
            if (v.z == 2 || v.z == 4) m0 |= 1u << (k + 2);
            if (v.z == 3 || v.z == 4) m1 |= 1u << (k + 2);
            if (v.w == 2 || v.w == 4) m0 |= 1u << (k + 3);
            if (v.w == 3 || v.w == 4) m1 |= 1u << (k + 3);
        }
        mask_l[0][s] = m0;
        mask_l[1][s] = m1;
    }

    float hacc[2][4];
#pragma unroll
    for (int a = 0; a < 2; ++a)
#pragma unroll
        for (int b = 0; b < 4; ++b) hacc[a][b] = 0.f;

    for (int j = 0; j < 2; ++j) {
        const int inst = bi * 2 + j;
        const int ij = i_ * 2 + j;
        const unsigned short* xpi = xpt + (size_t)inst * D_ * N_;

        __syncthreads();             // prev conv consumers done with LDS
        if (t < 128) ad_l[t] = att_dst[ij * D_ + t] * LOG2E;
        // ss_t <- ssg[inst]: 4096 floats as 1024 float4
        {
            const float4* src = (const float4*)(ssg + (size_t)inst * 8 * N_);
#pragma unroll
            for (int r = 0; r < 4; ++r)
                *((float4*)ss_t + r * 256 + t) = src[r * 256 + t];
        }
        __syncthreads();
        // sd for block's 16 dst x 8 h
        if (t < 128) {
            const int dd = t >> 3;
            const int hh = t & 7;
            float s = 0.f;
#pragma unroll
            for (int f = 0; f < 16; ++f)
                s += bf1(xpi[(size_t)(hh * 16 + f) * N_ + d0 + dd]) * ad_l[hh * 16 + f];
            sd_l[hh][dd] = s;
        }
        __syncthreads();             // ss_t, sd_l ready

        const float sdv[2] = { sd_l[h0][n], sd_l[h0 + 1][n] };

        floatx4 Cacc[2] = { (floatx4){0.f,0.f,0.f,0.f}, (floatx4){0.f,0.f,0.f,0.f} };
        float zacc[2] = { 0.f, 0.f };

        // software-prefetched, barrier-free K loop: 16 chunks of 32 s
        short8 Bf0 = *(const short8*)(xpi + (size_t)(h0 * 16 + n) * N_ + q * 8);
        short8 Bf1 = *(const short8*)(xpi + (size_t)((h0 + 1) * 16 + n) * N_ + q * 8);
        for (int c = 0; c < 16; ++c) {
            const int sq = c * 32 + q * 8;
            short8 nBf0, nBf1;
            if (c < 15) {
                nBf0 = *(const short8*)(xpi + (size_t)(h0 * 16 + n) * N_ + sq + 32);
                nBf1 = *(const short8*)(xpi + (size_t)((h0 + 1) * 16 + n) * N_ + sq + 32);
            }
            const uint4 m0v = *(const uint4*)&mask_l[j][sq];
            const uint4 m1v = *(const uint4*)&mask_l[j][sq + 4];
            const unsigned int mw[8] = { m0v.x, m0v.y, m0v.z, m0v.w,
                                         m1v.x, m1v.y, m1v.z, m1v.w };
#pragma unroll
            for (int hh2 = 0; hh2 < 2; ++hh2) {
                const float4 s0v = *(const float4*)&ss_t[(h0 + hh2) * N_ + sq];
                const float4 s1v = *(const float4*)&ss_t[(h0 + hh2) * N_ + sq + 4];
                const float ssv[8] = { s0v.x, s0v.y, s0v.z, s0v.w,
                                       s1v.x, s1v.y, s1v.z, s1v.w };
                unsigned int wt[8];
#pragma unroll
                for (int idx = 0; idx < 8; ++idx) {
                    const float z0 = ssv[idx] + sdv[hh2];
                    const float zr = fmaxf(z0, 0.2f * z0);
                    const float e = EXP2F(zr);
                    const float w = ((mw[idx] >> n) & 1u) ? e : 1.0f;
                    wt[idx] = __float_as_uint(w) & 0xffff0000u;
                    zacc[hh2] += __uint_as_float(wt[idx]);
                }
                uintx4 au;
                au.x = __builtin_amdgcn_perm(wt[1], wt[0], 0x07060302);
                au.y = __builtin_amdgcn_perm(wt[3], wt[2], 0x07060302);
                au.z = __builtin_amdgcn_perm(wt[5], wt[4], 0x07060302);
                au.w = __builtin_amdgcn_perm(wt[7], wt[6], 0x07060302);
                Cacc[hh2] = __builtin_amdgcn_mfma_f32_16x16x32_bf16(
                    __builtin_bit_cast(short8, au),
                    hh2 ? Bf1 : Bf0, Cacc[hh2], 0, 0, 0);
            }
            Bf0 = nBf0;
            Bf1 = nBf1;
        }

#pragma unroll
        for (int hh2 = 0; hh2 < 2; ++hh2) {
            float z = zacc[hh2];
            z += __shfl_xor(z, 16);
            z += __shfl_xor(z, 32);
            zacc[hh2] = z;
        }
        if (q == 0) { z_l[h0][n] = zacc[0]; z_l[h0 + 1][n] = zacc[1]; }

#pragma unroll
        for (int hh2 = 0; hh2 < 2; ++hh2) {
            const int h = h0 + hh2;
            const float bv = bias[ij * D_ + h * 16 + n];
            const uint2 sv = *(const uint2*)(xpi + (size_t)(h * 16 + n) * N_ + d0 + q * 4);
            const float selfv[4] = { bflo(sv.x), bfhi(sv.x), bflo(sv.y), bfhi(sv.y) };
#pragma unroll
            for (int reg = 0; reg < 4; ++reg) {
                const float Zi = 1.0f / z_l[h][q * 4 + reg];
                hacc[hh2][reg] += Cacc[hh2][reg] * Zi + selfv[reg] + bv;
            }
        }
    }

#pragma unroll
    for (int hh2 = 0; hh2 < 2; ++hh2)
#pragma unroll
        for (int reg = 0; reg < 4; ++reg)
            hout[((size_t)bi * N_ + d0 + q * 4 + reg) * D_ + (h0 + hh2) * 16 + n]
                = hacc[hh2][reg];
}

// ---------------------------------------------------------------------------
// Kernel 3: in-place mix on d_out (thread owns both i slices of one b).
// ---------------------------------------------------------------------------
__global__ __launch_bounds__(256) void combine_kernel(float* __restrict__ h)
{
    const int idx = blockIdx.x * 256 + threadIdx.x;
    const int b = idx >> 14;
    const int r = idx & 16383;
    float4* p0 = (float4*)h + (size_t)b * 32768 + r;
    float4* p1 = p0 + 16384;
    const float4 a = *p0;
    const float4 o = *p1;
    float4 r0, r1;
    r0.x = 1.5f * a.x + 0.5f * o.x;  r1.x = 1.5f * o.x + 0.5f * a.x;
    r0.y = 1.5f * a.y + 0.5f * o.y;  r1.y = 1.5f * o.y + 0.5f * a.y;
    r0.z = 1.5f * a.z + 0.5f * o.z;  r1.z = 1.5f * o.z + 0.5f * a.z;
    r0.w = 1.5f * a.w + 0.5f * o.w;  r1.w = 1.5f * o.w + 0.5f * a.w;
    *p0 = r0;
    *p1 = r1;
}

extern "C" void kernel_launch(void* const* d_in, const int* in_sizes, int n_in,
                              void* d_out, int out_size, void* d_ws, size_t ws_size,
                              hipStream_t stream)
{
    const float* x   = (const float*)d_in[0];
    const int*   A   = (const int*)d_in[1];
    const float* W   = (const float*)d_in[2];
    const float* pb  = (const float*)d_in[3];
    const float* as_ = (const float*)d_in[4];
    const float* ad_ = (const float*)d_in[5];
    const float* bs  = (const float*)d_in[6];

    unsigned short* xpt = (unsigned short*)d_ws;          // 8,388,608 B
    float* ssg = (float*)(xpt + (size_t)64 * D_ * N_);    // +1,048,576 B
    float* h = (float*)d_out;

    proj_kernel<<<1024, 256, 0, stream>>>(x, W, pb, as_, xpt, ssg);
    attn_kernel<<<1024, 256, 0, stream>>>(xpt, ssg, A, ad_, bs, h);
    combine_kernel<<<1024, 256, 0, stream>>>(h);
}

// Round 12
// 161.436 us; speedup vs baseline: 3.9758x; 1.0411x over previous
//
#include <hip/hip_runtime.h>

#define N_ 512
#define D_ 128
#define LOG2E 1.44269504088896f

// ws: [0, 8 MB)      xp_t bf16 TRANSPOSED [inst][f=128][s=512]   (8,388,608 B)
//     [8, 10.5 MB)   score_g fp32 [inst][kind:ss/sd][h=8][s=512] (2,097,152 B)
// h staged in d_out; combine mixes in place.

typedef __attribute__((ext_vector_type(8))) short short8;
typedef __attribute__((ext_vector_type(4))) float floatx4;
typedef __attribute__((ext_vector_type(4))) unsigned int uintx4;

#if defined(__has_builtin)
#if __has_builtin(__builtin_amdgcn_exp2f)
#define EXP2F(x) __builtin_amdgcn_exp2f(x)
#else
#define EXP2F(x) exp2f(x)
#endif
#else
#define EXP2F(x) exp2f(x)
#endif

__device__ __forceinline__ unsigned short f2bf(float f) {
    unsigned int u = __float_as_uint(f);
    u += 0x7fffu + ((u >> 16) & 1u);
    return (unsigned short)(u >> 16);
}
__device__ __forceinline__ float bflo(unsigned int u) { return __uint_as_float(u << 16); }
__device__ __forceinline__ float bfhi(unsigned int u) { return __uint_as_float(u & 0xffff0000u); }

// ---------------------------------------------------------------------------
// Kernel 1: proj via MFMA, no LDS/barriers; fused ss AND sd reductions.
// 2 blocks per (inst, 64-row ntile): half = bid&1 covers 4 f-tiles = 4 heads.
// Epilogue: xp_t bf16 store + 16-lane shfl reductions of ss/sd (log2-domain)
// into score_g. C/D: col=lane&15 (f), row=q*4+reg (n) [m89-verified].
// ---------------------------------------------------------------------------
__global__ __launch_bounds__(256) void proj_kernel(
    const float* __restrict__ x, const float* __restrict__ W,
    const float* __restrict__ pb, const float* __restrict__ att_src,
    const float* __restrict__ att_dst,
    unsigned short* __restrict__ xpt, float* __restrict__ sg)
{
    const int bid = blockIdx.x;
    const int unit = bid >> 1;      // 0..511
    const int half = bid & 1;
    const int ntile = unit & 7;
    const int inst  = unit >> 3;    // 0..63
    const int j = inst & 1;
    const int bi = inst >> 1;
    const int ij = (bi & 1) * 2 + j;
    const int t = threadIdx.x;
    const int wave = t >> 6, L = t & 63, n = L & 15, q = L >> 4;

    const int n0w = ntile * 64 + wave * 16;
    const float* xrow = x + ((size_t)bi * N_ + n0w + n) * D_ + q * 8;
    short8 Af[4];
#pragma unroll
    for (int kc = 0; kc < 4; ++kc) {
        const float4 a0 = *(const float4*)(xrow + kc * 32);
        const float4 a1 = *(const float4*)(xrow + kc * 32 + 4);
        uintx4 au;
        au.x = f2bf(a0.x) | ((unsigned int)f2bf(a0.y) << 16);
        au.y = f2bf(a0.z) | ((unsigned int)f2bf(a0.w) << 16);
        au.z = f2bf(a1.x) | ((unsigned int)f2bf(a1.y) << 16);
        au.w = f2bf(a1.z) | ((unsigned int)f2bf(a1.w) << 16);
        Af[kc] = __builtin_bit_cast(short8, au);
    }

    const float* wb = W + (size_t)ij * D_ * D_;
#pragma unroll
    for (int ft = 0; ft < 4; ++ft) {
        const int head = half * 4 + ft;
        const int fg = head * 16 + n;
        const float* wrow = wb + (size_t)fg * D_ + q * 8;
        floatx4 C = (floatx4){0.f, 0.f, 0.f, 0.f};
#pragma unroll
        for (int kc = 0; kc < 4; ++kc) {
            const float4 b0 = *(const float4*)(wrow + kc * 32);
            const float4 b1 = *(const float4*)(wrow + kc * 32 + 4);
            uintx4 bu;
            bu.x = f2bf(b0.x) | ((unsigned int)f2bf(b0.y) << 16);
            bu.y = f2bf(b0.z) | ((unsigned int)f2bf(b0.w) << 16);
            bu.z = f2bf(b1.x) | ((unsigned int)f2bf(b1.y) << 16);
            bu.w = f2bf(b1.z) | ((unsigned int)f2bf(b1.w) << 16);
            C = __builtin_amdgcn_mfma_f32_16x16x32_bf16(
                Af[kc], __builtin_bit_cast(short8, bu), C, 0, 0, 0);
        }
        const float pbv = pb[ij * D_ + fg];
        float xp0 = C[0] + pbv, xp1 = C[1] + pbv;
        float xp2 = C[2] + pbv, xp3 = C[3] + pbv;
        uint2 pk;
        pk.x = f2bf(xp0) | ((unsigned int)f2bf(xp1) << 16);
        pk.y = f2bf(xp2) | ((unsigned int)f2bf(xp3) << 16);
        *(uint2*)&xpt[((size_t)inst * D_ + fg) * N_ + n0w + q * 4] = pk;

        // ss and sd reductions over the 16 f-lanes of this head
        const float asv = att_src[ij * D_ + fg];
        const float adv = att_dst[ij * D_ + fg];
        float sa0 = xp0 * asv, sa1 = xp1 * asv, sa2 = xp2 * asv, sa3 = xp3 * asv;
        float sb0 = xp0 * adv, sb1 = xp1 * adv, sb2 = xp2 * adv, sb3 = xp3 * adv;
#pragma unroll
        for (int off = 1; off < 16; off <<= 1) {
            sa0 += __shfl_xor(sa0, off); sa1 += __shfl_xor(sa1, off);
            sa2 += __shfl_xor(sa2, off); sa3 += __shfl_xor(sa3, off);
            sb0 += __shfl_xor(sb0, off); sb1 += __shfl_xor(sb1, off);
            sb2 += __shfl_xor(sb2, off); sb3 += __shfl_xor(sb3, off);
        }
        if (n < 4) {
            const float v = (n == 0) ? sa0 : (n == 1) ? sa1 : (n == 2) ? sa2 : sa3;
            sg[(((size_t)inst * 2 + 0) * 8 + head) * N_ + n0w + q * 4 + n] = v * LOG2E;
        } else if (n >= 8 && n < 12) {
            const int r = n - 8;
            const float v = (r == 0) ? sb0 : (r == 1) ? sb1 : (r == 2) ? sb2 : sb3;
            sg[(((size_t)inst * 2 + 1) * 8 + head) * N_ + n0w + q * 4 + r] = v * LOG2E;
        }
    }
}

// ---------------------------------------------------------------------------
// Kernel 2: attention via MFMA. Block = (bi = bid>>5, 16-dst tile = bid&31);
// 4 waves, wave owns 2 heads, BOTH convs fused in one barrier-free K-loop
// (4 independent exp->MFMA chains). ss/sd precomputed by proj. Z computed by
// a second MFMA against an all-ones B (lands in C-layout; no shuffles/LDS).
// The v_perm pack truncates w to bf16, so Z and numerator use identical
// values. Masked entries: w = exp(0) = 1; softmax over all 512 src.
// Exactly ONE __syncthreads per block.
// ---------------------------------------------------------------------------
__global__ __launch_bounds__(256) void attn_kernel(
    const unsigned short* __restrict__ xpt,
    const float* __restrict__ sg,
    const int* __restrict__ A,
    const float* __restrict__ bias,
    float* __restrict__ hout)
{
    __shared__ float ss_t[2][8][N_];         // 32 KB [conv][h][s], log2-domain
    __shared__ unsigned int mask_l[2][N_];   // 4 KB

    const int bid = blockIdx.x;
    const int tile = bid & 31;
    const int bi   = bid >> 5;
    const int i_ = bi & 1;
    const int d0 = tile * 16;
    const int t = threadIdx.x;
    const int wave = t >> 6, L = t & 63, n = L & 15, q = L >> 4;
    const int h0 = wave * 2;

    // edge bitmasks for both convs (bit k = dst d0+k)
#pragma unroll
    for (int rep = 0; rep < 2; ++rep) {
        const int s = t + rep * 256;
        const int* Ar = A + ((size_t)bi * N_ + s) * N_ + d0;
        unsigned int m0 = 0, m1 = 0;
#pragma unroll
        for (int g = 0; g < 4; ++g) {
            const int4 v = *(const int4*)(Ar + g * 4);
            const int k = g * 4;
            if (v.x == 2 || v.x == 4) m0 |= 1u << (k + 0);
            if (v.x == 3 || v.x == 4) m1 |= 1u << (k + 0);
            if (v.y == 2 || v.y == 4) m0 |= 1u << (k + 1);
            if (v.y == 3 || v.y == 4) m1 |= 1u << (k + 1);
            if (v.z == 2 || v.z == 4) m0 |= 1u << (k + 2);
            if (v.z == 3 || v.z == 4) m1 |= 1u << (k + 2);
            if (v.w == 2 || v.w == 4) m0 |= 1u << (k + 3);
            if (v.w == 3 || v.w == 4) m1 |= 1u << (k + 3);
        }
        mask_l[0][s] = m0;
        mask_l[1][s] = m1;
    }

    // stage ss for both convs: 1024 float4 per conv, 4 per thread
#pragma unroll
    for (int j = 0; j < 2; ++j) {
        const float4* src = (const float4*)(sg + (size_t)((bi * 2 + j) * 2) * 8 * N_);
        float4* dst = (float4*)&ss_t[j][0][0];
#pragma unroll
        for (int r = 0; r < 4; ++r) dst[r * 256 + t] = src[r * 256 + t];
    }

    // sd: 4 direct global loads per lane (broadcast within quad)
    float sdv[2][2];
#pragma unroll
    for (int j = 0; j < 2; ++j)
#pragma unroll
        for (int hh = 0; hh < 2; ++hh)
            sdv[j][hh] = sg[(((size_t)(bi * 2 + j) * 2 + 1) * 8 + h0 + hh) * N_ + d0 + n];

    __syncthreads();   // masks + ss_t ready (the ONLY barrier)

    const unsigned short* xpi[2] = { xpt + (size_t)(bi * 2) * D_ * N_,
                                     xpt + (size_t)(bi * 2 + 1) * D_ * N_ };

    const uintx4 ou = { 0x3F803F80u, 0x3F803F80u, 0x3F803F80u, 0x3F803F80u };
    const short8 onesB = __builtin_bit_cast(short8, ou);

    floatx4 Cacc[2][2], Cz[2][2];
#pragma unroll
    for (int j = 0; j < 2; ++j)
#pragma unroll
        for (int hh = 0; hh < 2; ++hh) {
            Cacc[j][hh] = (floatx4){0.f, 0.f, 0.f, 0.f};
            Cz[j][hh]   = (floatx4){0.f, 0.f, 0.f, 0.f};
        }

    for (int c = 0; c < 16; ++c) {
        const int sq = c * 32 + q * 8;
        short8 Bf[2][2];
#pragma unroll
        for (int j = 0; j < 2; ++j) {
            Bf[j][0] = *(const short8*)(xpi[j] + (size_t)(h0 * 16 + n) * N_ + sq);
            Bf[j][1] = *(const short8*)(xpi[j] + (size_t)((h0 + 1) * 16 + n) * N_ + sq);
        }
        const uint4 ma0 = *(const uint4*)&mask_l[0][sq];
        const uint4 ma1 = *(const uint4*)&mask_l[0][sq + 4];
        const uint4 mb0 = *(const uint4*)&mask_l[1][sq];
        const uint4 mb1 = *(const uint4*)&mask_l[1][sq + 4];
        const unsigned int mw[2][8] = {
            { ma0.x, ma0.y, ma0.z, ma0.w, ma1.x, ma1.y, ma1.z, ma1.w },
            { mb0.x, mb0.y, mb0.z, mb0.w, mb1.x, mb1.y, mb1.z, mb1.w } };
#pragma unroll
        for (int j = 0; j < 2; ++j) {
#pragma unroll
            for (int hh = 0; hh < 2; ++hh) {
                const float4 s0v = *(const float4*)&ss_t[j][h0 + hh][sq];
                const float4 s1v = *(const float4*)&ss_t[j][h0 + hh][sq + 4];
                const float ssv[8] = { s0v.x, s0v.y, s0v.z, s0v.w,
                                       s1v.x, s1v.y, s1v.z, s1v.w };
                unsigned int wt[8];
#pragma unroll
                for (int idx = 0; idx < 8; ++idx) {
                    const float z0 = ssv[idx] + sdv[j][hh];
                    const float zr = fmaxf(z0, 0.2f * z0);
                    const float e = EXP2F(zr);
                    wt[idx] = __float_as_uint(((mw[j][idx] >> n) & 1u) ? e : 1.0f);
                }
                uintx4 au;   // v_perm keeps bytes 3:2 of each src = bf16 trunc
                au.x = __builtin_amdgcn_perm(wt[1], wt[0], 0x07060302);
                au.y = __builtin_amdgcn_perm(wt[3], wt[2], 0x07060302);
                au.z = __builtin_amdgcn_perm(wt[5], wt[4], 0x07060302);
                au.w = __builtin_amdgcn_perm(wt[7], wt[6], 0x07060302);
                const short8 As = __builtin_bit_cast(short8, au);
                Cacc[j][hh] = __builtin_amdgcn_mfma_f32_16x16x32_bf16(
                    As, Bf[j][hh], Cacc[j][hh], 0, 0, 0);
                Cz[j][hh] = __builtin_amdgcn_mfma_f32_16x16x32_bf16(
                    As, onesB, Cz[j][hh], 0, 0, 0);
            }
        }
    }

    // epilogue: hacc = sum_j [ C/Z + xp_self + bias ]
    float hacc[2][4];
#pragma unroll
    for (int hh = 0; hh < 2; ++hh)
#pragma unroll
        for (int reg = 0; reg < 4; ++reg) hacc[hh][reg] = 0.f;

#pragma unroll
    for (int j = 0; j < 2; ++j) {
        const int ij = i_ * 2 + j;
#pragma unroll
        for (int hh = 0; hh < 2; ++hh) {
            const int h = h0 + hh;
            const float bv = bias[ij * D_ + h * 16 + n];
            const uint2 sv = *(const uint2*)(xpi[j] + (size_t)(h * 16 + n) * N_ + d0 + q * 4);
            const float selfv[4] = { bflo(sv.x), bfhi(sv.x), bflo(sv.y), bfhi(sv.y) };
#pragma unroll
            for (int reg = 0; reg < 4; ++reg) {
                const float Zi = 1.0f / Cz[j][hh][reg];
                hacc[hh][reg] += Cacc[j][hh][reg] * Zi + selfv[reg] + bv;
            }
        }
    }

#pragma unroll
    for (int hh = 0; hh < 2; ++hh)
#pragma unroll
        for (int reg = 0; reg < 4; ++reg)
            hout[((size_t)bi * N_ + d0 + q * 4 + reg) * D_ + (h0 + hh) * 16 + n]
                = hacc[hh][reg];
}

// ---------------------------------------------------------------------------
// Kernel 3: in-place mix on d_out (thread owns both i slices of one b).
// ---------------------------------------------------------------------------
__global__ __launch_bounds__(256) void combine_kernel(float* __restrict__ h)
{
    const int idx = blockIdx.x * 256 + threadIdx.x;
    const int b = idx >> 14;
    const int r = idx & 16383;
    float4* p0 = (float4*)h + (size_t)b * 32768 + r;
    float4* p1 = p0 + 16384;
    const float4 a = *p0;
    const float4 o = *p1;
    float4 r0, r1;
    r0.x = 1.5f * a.x + 0.5f * o.x;  r1.x = 1.5f * o.x + 0.5f * a.x;
    r0.y = 1.5f * a.y + 0.5f * o.y;  r1.y = 1.5f * o.y + 0.5f * a.y;
    r0.z = 1.5f * a.z + 0.5f * o.z;  r1.z = 1.5f * o.z + 0.5f * a.z;
    r0.w = 1.5f * a.w + 0.5f * o.w;  r1.w = 1.5f * o.w + 0.5f * a.w;
    *p0 = r0;
    *p1 = r1;
}

extern "C" void kernel_launch(void* const* d_in, const int* in_sizes, int n_in,
                              void* d_out, int out_size, void* d_ws, size_t ws_size,
                              hipStream_t stream)
{
    const float* x   = (const float*)d_in[0];
    const int*   A   = (const int*)d_in[1];
    const float* W   = (const float*)d_in[2];
    const float* pb  = (const float*)d_in[3];
    const float* as_ = (const float*)d_in[4];
    const float* ad_ = (const float*)d_in[5];
    const float* bs  = (const float*)d_in[6];

    unsigned short* xpt = (unsigned short*)d_ws;          // 8,388,608 B
    float* sg = (float*)(xpt + (size_t)64 * D_ * N_);     // +2,097,152 B
    float* h = (float*)d_out;

    proj_kernel<<<1024, 256, 0, stream>>>(x, W, pb, as_, ad_, xpt, sg);
    attn_kernel<<<1024, 256, 0, stream>>>(xpt, sg, A, bs, h);
    combine_kernel<<<1024, 256, 0, stream>>>(h);
}